// Round 2
// baseline (3949.478 us; speedup 1.0000x reference)
//
#include <hip/hip_runtime.h>
#include <hip/hip_bf16.h>
#include <math.h>

#define BB 8
#define CC 256
#define HH 128
#define WW 128
#define HWSZ (HH*WW)              // 16384
#define NTOT ((size_t)BB*CC*HWSZ) // 33554432 elements

typedef __hip_bfloat16 bf16;

__device__ __forceinline__ float ldf(const float* p) { return *p; }
__device__ __forceinline__ float ldf(const bf16* p) { return __bfloat162float(*p); }
__device__ __forceinline__ void stf(float* p, float v) { *p = v; }
__device__ __forceinline__ void stf(bf16* p, float v) { *p = __float2bfloat16(v); }

// ---------------------------------------------------------------- pool 3x3
__global__ __launch_bounds__(256) void pool3_kernel(const float* __restrict__ x,
                                                    bf16* __restrict__ yavg,
                                                    bf16* __restrict__ ymax) {
    size_t idx = (size_t)blockIdx.x * 256 + threadIdx.x; // over NTOT
    int w = idx & (WW - 1);
    int h = (idx >> 7) & (HH - 1);
    size_t bc = idx >> 14;
    const float* base = x + bc * HWSZ;
    float s = 0.f, mx = -INFINITY;
#pragma unroll
    for (int dy = -1; dy <= 1; ++dy) {
        int hh = h + dy; if (hh < 0 || hh >= HH) continue;
#pragma unroll
        for (int dx = -1; dx <= 1; ++dx) {
            int ww = w + dx; if (ww < 0 || ww >= WW) continue;
            float v = base[hh * WW + ww];
            s += v; mx = fmaxf(mx, v);
        }
    }
    stf(&yavg[idx], s * (1.f / 9.f)); // count_include_pad=True -> always /9
    stf(&ymax[idx], mx);              // zero-pad excluded from max (-inf)
}

// ---------------------------------------------------------------- conv1x1 GEMM
#define EPI_NONE   0
#define EPI_RELU   1
#define EPI_ADDAUX 2
#define EPI_SIGMUL 3

template<int MODE, bool TWO_IN, bool HAS_SCALE, bool HAS_V,
         class TIN1, class TIN2, class TAUX, class TOUT>
__global__ __launch_bounds__(256) void conv1x1_kernel(
    TOUT* __restrict__ out,
    const TIN1* __restrict__ in1,
    const TIN2* __restrict__ in2,
    const float* __restrict__ Wm, int WS,
    const float* __restrict__ bias,
    const TAUX* __restrict__ aux,
    const float* __restrict__ scale,   // per (b, in-chan) gate
    const float* __restrict__ vvec,    // per (b, pixel) scalar (V column)
    const float* __restrict__ vw)      // = Wm + 512 (stride WS)
{
    const int K = TWO_IN ? 512 : 256;
    __shared__ float Ws[16][64];
    __shared__ float Xs[16][64];
    int tid = threadIdx.x;
    int b = blockIdx.z;
    int o0 = blockIdx.y * 64, p0 = blockIdx.x * 64;
    int tx = tid & 15, ty = tid >> 4;
    float acc[4][4] = {};
    int woo = tid >> 2, wkb = (tid & 3) * 4;
    int xpp = tid & 63, xkr = tid >> 6;

    for (int k0 = 0; k0 < K; k0 += 16) {
        const float* wrow = Wm + (size_t)(o0 + woo) * WS + k0 + wkb;
#pragma unroll
        for (int r = 0; r < 4; ++r) Ws[wkb + r][woo] = wrow[r];
#pragma unroll
        for (int pass = 0; pass < 4; ++pass) {
            int kk = xkr + pass * 4;
            int c = k0 + kk;
            float v;
            if (TWO_IN && c >= 256) {
                v = ldf(&in2[((size_t)b * 256 + (c - 256)) * HWSZ + p0 + xpp]);
            } else {
                v = ldf(&in1[((size_t)b * 256 + c) * HWSZ + p0 + xpp]);
                if (HAS_SCALE) v *= scale[b * 256 + c];
            }
            Xs[kk][xpp] = v;
        }
        __syncthreads();
#pragma unroll
        for (int kk = 0; kk < 16; ++kk) {
            float a0[4], b0[4];
#pragma unroll
            for (int i = 0; i < 4; ++i) a0[i] = Ws[kk][ty * 4 + i];
#pragma unroll
            for (int j = 0; j < 4; ++j) b0[j] = Xs[kk][tx * 4 + j];
#pragma unroll
            for (int i = 0; i < 4; ++i)
#pragma unroll
                for (int j = 0; j < 4; ++j) acc[i][j] += a0[i] * b0[j];
        }
        __syncthreads();
    }
#pragma unroll
    for (int i = 0; i < 4; ++i) {
        int o = o0 + ty * 4 + i;
        float bs = bias[o];
        float vwo = HAS_V ? vw[(size_t)o * WS] : 0.f;
#pragma unroll
        for (int j = 0; j < 4; ++j) {
            int p = p0 + tx * 4 + j;
            size_t oidx = ((size_t)b * CC + o) * HWSZ + p;
            float val = acc[i][j] + bs;
            if (HAS_V) val += vwo * vvec[(size_t)b * HWSZ + p];
            if (MODE == EPI_RELU)        val = fmaxf(val, 0.f);
            else if (MODE == EPI_ADDAUX) val += ldf(&aux[oidx]);
            else if (MODE == EPI_SIGMUL) val = (1.f / (1.f + __expf(-val))) * ldf(&aux[oidx]);
            stf(&out[oidx], val);
        }
    }
}

// ---------------------------------------------------------------- CA reduce
__global__ __launch_bounds__(256) void ca_reduce_kernel(const float* __restrict__ xc,
                                                        float* __restrict__ avgv,
                                                        float* __restrict__ maxv) {
    int bc = blockIdx.x; // 0..2047
    const float* base = xc + (size_t)bc * HWSZ;
    float s = 0.f, mx = -INFINITY;
    for (int i = threadIdx.x; i < HWSZ; i += 256) {
        float v = base[i]; s += v; mx = fmaxf(mx, v);
    }
    for (int off = 32; off; off >>= 1) {
        s += __shfl_down(s, off);
        mx = fmaxf(mx, __shfl_down(mx, off));
    }
    __shared__ float ss[4], sm[4];
    int wid = threadIdx.x >> 6, lane = threadIdx.x & 63;
    if (lane == 0) { ss[wid] = s; sm[wid] = mx; }
    __syncthreads();
    if (threadIdx.x == 0) {
        float S = ss[0] + ss[1] + ss[2] + ss[3];
        float M = fmaxf(fmaxf(sm[0], sm[1]), fmaxf(sm[2], sm[3]));
        avgv[bc] = S * (1.f / HWSZ);
        maxv[bc] = M;
    }
}

// ---------------------------------------------------------------- CA MLP (tiny)
__global__ __launch_bounds__(256) void ca_mlp_kernel(
    const float* __restrict__ avgv, const float* __restrict__ maxv,
    const float* __restrict__ aw1, const float* __restrict__ ab1,
    const float* __restrict__ aw2, const float* __restrict__ ab2,
    const float* __restrict__ mw1, const float* __restrict__ mb1,
    const float* __restrict__ mw2, const float* __restrict__ mb2,
    float* __restrict__ gate) {
    int b = blockIdx.x;
    __shared__ float av[256], mv[256], ha[16], hm[16];
    int t = threadIdx.x;
    av[t] = avgv[b * 256 + t];
    mv[t] = maxv[b * 256 + t];
    __syncthreads();
    if (t < 16) {
        float s = ab1[t];
        for (int i = 0; i < 256; ++i) s += aw1[t * 256 + i] * av[i];
        ha[t] = fmaxf(s, 0.f);
    } else if (t < 32) {
        int r = t - 16;
        float s = mb1[r];
        for (int i = 0; i < 256; ++i) s += mw1[r * 256 + i] * mv[i];
        hm[r] = fmaxf(s, 0.f);
    }
    __syncthreads();
    float ya = ab2[t], ym = mb2[t];
    for (int r = 0; r < 16; ++r) {
        ya += aw2[t * 16 + r] * ha[r];
        ym += mw2[t * 16 + r] * hm[r];
    }
    float g = ya + ym;
    gate[b * 256 + t] = 1.f / (1.f + __expf(-g));
}

// ---------------------------------------------------------------- attention logits+softmax
// per (b,h): logits[i,j] = sum_c Q[b,c,h,i]*S[b,c,h,j]; softmax over j.
// STORE_M: write P (bf16) to Mout [b,h,i,j]. else: colsum over i -> m0 = 1-(colsum>0.1)
template<bool STORE_M>
__global__ __launch_bounds__(256) void attn_kernel(
    const bf16* __restrict__ Q, const bf16* __restrict__ S,
    bf16* __restrict__ Mout, float* __restrict__ m0out)
{
    int bh = blockIdx.x; int b = bh >> 7, h = bh & 127;
    const bf16* Qb = Q + (size_t)b * CC * HWSZ + h * WW;
    const bf16* Sb = S + (size_t)b * CC * HWSZ + h * WW;
    __shared__ float Qs[16][128];
    __shared__ float Ss[16][128];
    int tid = threadIdx.x;
    int tx = tid & 15, ty = tid >> 4;
    float acc[8][8] = {};
    int lk = tid >> 4;
    int li = (tid & 15) * 8;
    for (int c0 = 0; c0 < 256; c0 += 16) {
#pragma unroll
        for (int r = 0; r < 8; ++r) {
            Qs[lk][li + r] = ldf(&Qb[(size_t)(c0 + lk) * HWSZ + li + r]);
            Ss[lk][li + r] = ldf(&Sb[(size_t)(c0 + lk) * HWSZ + li + r]);
        }
        __syncthreads();
#pragma unroll
        for (int kk = 0; kk < 16; ++kk) {
            float qa[8], sb2[8];
#pragma unroll
            for (int r = 0; r < 8; ++r) qa[r] = Qs[kk][ty * 8 + r];
#pragma unroll
            for (int q = 0; q < 8; ++q) sb2[q] = Ss[kk][tx * 8 + q];
#pragma unroll
            for (int r = 0; r < 8; ++r)
#pragma unroll
                for (int q = 0; q < 8; ++q) acc[r][q] += qa[r] * sb2[q];
        }
        __syncthreads();
    }
    // row softmax: row i=ty*8+r spread over 16 consecutive tx-lanes
#pragma unroll
    for (int r = 0; r < 8; ++r) {
        float mx = acc[r][0];
#pragma unroll
        for (int q = 1; q < 8; ++q) mx = fmaxf(mx, acc[r][q]);
        for (int m = 1; m < 16; m <<= 1) mx = fmaxf(mx, __shfl_xor(mx, m));
        float sm = 0.f;
#pragma unroll
        for (int q = 0; q < 8; ++q) { float e = __expf(acc[r][q] - mx); acc[r][q] = e; sm += e; }
        for (int m = 1; m < 16; m <<= 1) sm += __shfl_xor(sm, m);
        float inv = 1.f / sm;
#pragma unroll
        for (int q = 0; q < 8; ++q) acc[r][q] *= inv;
    }
    if (STORE_M) {
        bf16* Mb = Mout + (size_t)bh * WW * WW;
#pragma unroll
        for (int r = 0; r < 8; ++r) {
            int i = ty * 8 + r;
#pragma unroll
            for (int q = 0; q < 8; ++q) stf(&Mb[i * WW + tx * 8 + q], acc[r][q]);
        }
    } else {
        __shared__ float cs[16][128];
#pragma unroll
        for (int q = 0; q < 8; ++q) {
            float s = 0.f;
#pragma unroll
            for (int r = 0; r < 8; ++r) s += acc[r][q];
            cs[ty][tx * 8 + q] = s;
        }
        __syncthreads();
        if (tid < 128) {
            float s = 0.f;
#pragma unroll
            for (int g = 0; g < 16; ++g) s += cs[g][tid];
            m0out[(size_t)b * HWSZ + h * WW + tid] = (s > 0.1f) ? 0.f : 1.f;
        }
    }
}

// ---------------------------------------------------------------- attention apply
// out[b,c,h,i] = sum_j M[b,h,i,j] * v3[b,c,h,j]
__global__ __launch_bounds__(256) void attn_apply_kernel(
    const bf16* __restrict__ Mbuf, const bf16* __restrict__ v3,
    bf16* __restrict__ outb)
{
    int bh = blockIdx.x; int b = bh >> 7, h = bh & 127;
    int ch0 = blockIdx.y * 128;
    const bf16* Mb = Mbuf + (size_t)bh * WW * WW;
    const bf16* Vb = v3 + ((size_t)b * CC + ch0) * HWSZ + h * WW;
    bf16* Ob = outb + ((size_t)b * CC + ch0) * HWSZ + h * WW;
    __shared__ float Ms[16][132]; // [jj][i]
    __shared__ float Vs[16][132]; // [jj][c]
    int tid = threadIdx.x;
    int tx = tid & 15, ty = tid >> 4;
    float acc[8][8] = {}; // [cc][ii]
    int lr = tid >> 1;
    int ljb = (tid & 1) * 8;
    for (int j0 = 0; j0 < 128; j0 += 16) {
#pragma unroll
        for (int r = 0; r < 8; ++r) {
            Ms[ljb + r][lr] = ldf(&Mb[lr * WW + j0 + ljb + r]);
            Vs[ljb + r][lr] = ldf(&Vb[(size_t)lr * HWSZ + j0 + ljb + r]);
        }
        __syncthreads();
#pragma unroll
        for (int jj = 0; jj < 16; ++jj) {
            float mv[8], vv[8];
#pragma unroll
            for (int ii = 0; ii < 8; ++ii) mv[ii] = Ms[jj][tx * 8 + ii];
#pragma unroll
            for (int ccx = 0; ccx < 8; ++ccx) vv[ccx] = Vs[jj][ty * 8 + ccx];
#pragma unroll
            for (int ccx = 0; ccx < 8; ++ccx)
#pragma unroll
                for (int ii = 0; ii < 8; ++ii) acc[ccx][ii] += vv[ccx] * mv[ii];
        }
        __syncthreads();
    }
#pragma unroll
    for (int ccx = 0; ccx < 8; ++ccx) {
        int c = ty * 8 + ccx;
#pragma unroll
        for (int ii = 0; ii < 8; ++ii)
            stf(&Ob[(size_t)c * HWSZ + tx * 8 + ii], acc[ccx][ii]);
    }
}

// ---------------------------------------------------------------- morphology
__global__ void morph_kernel(const float* __restrict__ in, float* __restrict__ out,
                             int Hd, int Wd, int r, float thresh) {
    int idx = blockIdx.x * 256 + threadIdx.x;
    int tot = BB * Hd * Wd;
    if (idx >= tot) return;
    int x = idx % Wd; int y = (idx / Wd) % Hd; int b = idx / (Wd * Hd);
    const float* base = in + (size_t)b * Hd * Wd;
    float s = 0.f;
    for (int dy = -r; dy <= r; ++dy) {
        int yy = y + dy; if (yy < 0 || yy >= Hd) continue;
        for (int dx = -r; dx <= r; ++dx) {
            if (dx * dx + dy * dy > r * r) continue;
            int xx = x + dx; if (xx < 0 || xx >= Wd) continue;
            s += base[yy * Wd + xx];
        }
    }
    out[idx] = (s > thresh) ? 1.f : 0.f;
}

__global__ void pad3_kernel(const float* __restrict__ in, float* __restrict__ out) {
    int idx = blockIdx.x * 256 + threadIdx.x;
    int tot = BB * 134 * 134; if (idx >= tot) return;
    int x = idx % 134; int y = (idx / 134) % 134; int b = idx / (134 * 134);
    float v = 0.f;
    int xs = x - 3, ys = y - 3;
    if (xs >= 0 && xs < 128 && ys >= 0 && ys < 128)
        v = in[((size_t)b * 128 + ys) * 128 + xs];
    out[idx] = v;
}

__global__ void vfinal_kernel(const float* __restrict__ in, float* __restrict__ V) {
    int idx = blockIdx.x * 256 + threadIdx.x; // B*HWSZ
    if (idx >= BB * HWSZ) return;
    int x = idx & 127; int y = (idx >> 7) & 127; int b = idx >> 14;
    V[idx] = 1.f - in[((size_t)b * 134 + y + 3) * 134 + (x + 3)];
}

// ---------------------------------------------------------------- launch
extern "C" void kernel_launch(void* const* d_in, const int* in_sizes, int n_in,
                              void* d_out, int out_size, void* d_ws, size_t ws_size,
                              hipStream_t stream) {
    const float* x_p   = (const float*)d_in[0];
    const float* x_c   = (const float*)d_in[1];
    const float* pa_w1 = (const float*)d_in[2];
    const float* pa_b1 = (const float*)d_in[3];
    const float* pa_w2 = (const float*)d_in[4];
    const float* pa_b2 = (const float*)d_in[5];
    const float* pa_wc = (const float*)d_in[6];
    const float* pa_bc = (const float*)d_in[7];
    const float* ca_aw1 = (const float*)d_in[8];
    const float* ca_ab1 = (const float*)d_in[9];
    const float* ca_aw2 = (const float*)d_in[10];
    const float* ca_ab2 = (const float*)d_in[11];
    const float* ca_mw1 = (const float*)d_in[12];
    const float* ca_mb1 = (const float*)d_in[13];
    const float* ca_mw2 = (const float*)d_in[14];
    const float* ca_mb2 = (const float*)d_in[15];
    const float* b1_w  = (const float*)d_in[16];
    const float* b1_b  = (const float*)d_in[17];
    const float* b2_w  = (const float*)d_in[18];
    const float* b2_b  = (const float*)d_in[19];
    const float* b3_w  = (const float*)d_in[20];
    const float* b3_b  = (const float*)d_in[21];
    const float* fus_w = (const float*)d_in[22];
    const float* fus_b = (const float*)d_in[23];
    float* out = (float*)d_out;

    // ws layout (total ~129.6 MiB): two full bf16 buffers + small fp32 scratch
    char* wsb = (char*)d_ws;
    bf16* A  = (bf16*)wsb;                    // NTOT bf16 (64 MiB)
    bf16* Bb = (bf16*)(wsb + NTOT * 2);       // NTOT bf16 (64 MiB)
    float* smalls = (float*)(wsb + NTOT * 4);
    float* avgv = smalls;                     // 2048
    float* maxv = smalls + 2048;              // 2048
    float* gate = smalls + 4096;              // 2048
    float* mph0 = smalls + 6144;              // 143648
    float* mph1 = mph0 + 143648;              // 143648
    float* Vfin = mph1 + 143648;              // 131072
    // d_out doubles as two bf16 scratch buffers until the final fusion conv
    bf16* D1 = (bf16*)d_out;                  // NTOT bf16
    bf16* D2 = D1 + NTOT;                     // NTOT bf16
    bf16* Mbuf = D1;                          // 16.7M bf16 (32 MiB), lives in D1 later

    dim3 cgrid(HWSZ / 64, CC / 64, BB);
    const int TPB = 256;

    // --- PALayer ---
    pool3_kernel<<<NTOT / 256, TPB, 0, stream>>>(x_p, A, Bb); // y1->A, y2->Bb
    conv1x1_kernel<EPI_RELU, false, false, false, bf16, bf16, bf16, bf16>
        <<<cgrid, TPB, 0, stream>>>(D1, A, nullptr, pa_w1, 256, pa_b1,
                                    nullptr, nullptr, nullptr, nullptr);          // z1->D1
    conv1x1_kernel<EPI_ADDAUX, false, false, false, bf16, bf16, bf16, bf16>
        <<<cgrid, TPB, 0, stream>>>(D2, D1, nullptr, pa_w2, 256, pa_b2,
                                    A, nullptr, nullptr, nullptr);                // u=conv(z1)+y1 ->D2
    conv1x1_kernel<EPI_RELU, false, false, false, bf16, bf16, bf16, bf16>
        <<<cgrid, TPB, 0, stream>>>(A, Bb, nullptr, pa_w1, 256, pa_b1,
                                    nullptr, nullptr, nullptr, nullptr);          // z2->A
    conv1x1_kernel<EPI_ADDAUX, false, false, false, bf16, bf16, bf16, bf16>
        <<<cgrid, TPB, 0, stream>>>(D1, A, nullptr, pa_w2, 256, pa_b2,
                                    Bb, nullptr, nullptr, nullptr);               // v=conv(z2)+y2 ->D1
    conv1x1_kernel<EPI_SIGMUL, true, false, false, bf16, bf16, float, bf16>
        <<<cgrid, TPB, 0, stream>>>(A, D2, D1, pa_wc, 512, pa_bc,
                                    x_p, nullptr, nullptr, nullptr);              // buffer_p->A

    // --- CALayer gate ---
    ca_reduce_kernel<<<BB * CC, TPB, 0, stream>>>(x_c, avgv, maxv);
    ca_mlp_kernel<<<BB, TPB, 0, stream>>>(avgv, maxv, ca_aw1, ca_ab1, ca_aw2, ca_ab2,
                                          ca_mw1, ca_mb1, ca_mw2, ca_mb2, gate);

    // --- Q/S projections (buffer_c = gate * x_c fused via per-channel scale) ---
    conv1x1_kernel<EPI_NONE, false, false, false, bf16, bf16, bf16, bf16>
        <<<cgrid, TPB, 0, stream>>>(Bb, A, nullptr, b1_w, 256, b1_b,
                                    nullptr, nullptr, nullptr, nullptr);          // Q1->Bb
    conv1x1_kernel<EPI_NONE, false, false, false, bf16, bf16, bf16, bf16>
        <<<cgrid, TPB, 0, stream>>>(D1, A, nullptr, b2_w, 256, b2_b,
                                    nullptr, nullptr, nullptr, nullptr);          // S2->D1
    conv1x1_kernel<EPI_NONE, false, true, false, float, float, float, bf16>
        <<<cgrid, TPB, 0, stream>>>(A, x_c, nullptr, b1_w, 256, b1_b,
                                    nullptr, gate, nullptr, nullptr);             // Q2->A
    conv1x1_kernel<EPI_NONE, false, true, false, float, float, float, bf16>
        <<<cgrid, TPB, 0, stream>>>(D2, x_c, nullptr, b2_w, 256, b2_b,
                                    nullptr, gate, nullptr, nullptr);             // S1->D2

    // --- attention softmaxes ---
    attn_kernel<false><<<BB * HH, TPB, 0, stream>>>(A, D1, nullptr, mph0);  // M_p_to_c colsum -> m0
    attn_kernel<true><<<BB * HH, TPB, 0, stream>>>(Bb, D2, Mbuf, nullptr);  // M_c_to_p -> Mbuf (D1)

    // --- v3 (independent of D1/D2 now) ---
    conv1x1_kernel<EPI_NONE, false, false, false, float, float, float, bf16>
        <<<cgrid, TPB, 0, stream>>>(A, x_c, nullptr, b3_w, 256, b3_b,
                                    nullptr, nullptr, nullptr, nullptr);          // v3->A

    // --- morphology (tiny) ---
    morph_kernel<<<512, TPB, 0, stream>>>(mph0, mph1, 128, 128, 2, 12.5f); // erode d2 (|d2|=13)
    morph_kernel<<<512, TPB, 0, stream>>>(mph1, mph0, 128, 128, 2, 0.5f);  // dilate d2
    morph_kernel<<<512, TPB, 0, stream>>>(mph0, mph1, 128, 128, 1, 0.5f);  // dilate d1
    morph_kernel<<<512, TPB, 0, stream>>>(mph1, mph0, 128, 128, 1, 4.5f);  // erode d1 (|d1|=5)
    pad3_kernel<<<562, TPB, 0, stream>>>(mph0, mph1);
    morph_kernel<<<562, TPB, 0, stream>>>(mph1, mph0, 134, 134, 3, 0.5f);  // dilate d3
    morph_kernel<<<562, TPB, 0, stream>>>(mph0, mph1, 134, 134, 3, 28.5f); // erode d3 (|d3|=29)
    vfinal_kernel<<<512, TPB, 0, stream>>>(mph1, Vfin);

    // --- attend + fusion ---
    attn_apply_kernel<<<dim3(BB * HH, 2), TPB, 0, stream>>>(Mbuf, A, Bb);  // bufA->Bb (over dead Q1)
    conv1x1_kernel<EPI_NONE, true, false, true, bf16, float, float, float>
        <<<cgrid, TPB, 0, stream>>>(out, Bb, x_p, fus_w, 513, fus_b,
                                    nullptr, nullptr, Vfin, fus_w + 512);         // final -> d_out fp32
}